// Round 15
// baseline (139.417 us; speedup 1.0000x reference)
//
#include <hip/hip_runtime.h>
#include <hip/hip_bf16.h>

// RelationCos pipeline in 3 kernels:
//   K1: FPS (blocks 0-15, packed-u64 argmax + LDS coord table) || W->bf16 packed (16-255)
//   K2: KNN (512 blocks, 8 waves; packed-u64) -> idx in ws
//   K3: stage-ALL-A gather GEMM: block = 4 queries x ALL 1024 cols, 132KB LDS
//       (A fully resident, pad-8 rows), ONE barrier, then barrier-free compute:
//       32 k-steps x {4 ds_read_b128 + 8 dense B-loads + 32 MFMA}. 1 block/CU.

#define NPTS 8192
#define SPTS 32
#define KNN_K 12
#define DS 256
#define DT 1024
#define DOUT 1024

typedef float f32x4 __attribute__((ext_vector_type(4)));
typedef __bf16 bf16x8 __attribute__((ext_vector_type(8)));
typedef unsigned short ushort_t;
typedef unsigned long long u64;

__device__ __forceinline__ ushort_t f2bf(float f) {
    unsigned int u = __float_as_uint(f);
    u += 0x7fffu + ((u >> 16) & 1u);   // RNE
    return (ushort_t)(u >> 16);
}

__device__ __forceinline__ ushort4 cvt4(float4 v) {
    ushort4 u;
    u.x = f2bf(v.x); u.y = f2bf(v.y); u.z = f2bf(v.z); u.w = f2bf(v.w);
    return u;
}

// ==================== K1: FPS || W convert (packed) ====================
// Packed layout: element (col,k) -> [k>>5]*(DOUT*32) + col*32 + (k&31)
__global__ __launch_bounds__(512) void fps_convw_kernel(const float* __restrict__ xyz,
                                                        float* __restrict__ new_xyz,
                                                        const float* __restrict__ Wt,
                                                        ushort_t* __restrict__ Wb_t,
                                                        const float* __restrict__ Ws,
                                                        ushort_t* __restrict__ Wb_s) {
    int bid = blockIdx.x;
    int tid = threadIdx.x;

    if (bid >= 16) {
        int lin = (bid - 16) * 512 + tid;
        const int stride = 240 * 512;
        for (int i = lin; i < (DT * DOUT) / 4; i += stride) {   // t: KD=1024
            int col = i >> 8, k4 = i & 255;
            float4 v = reinterpret_cast<const float4*>(Wt)[i];
            size_t off = (size_t)(k4 >> 3) * (DOUT * 32) + col * 32 + (k4 & 7) * 4;
            *reinterpret_cast<ushort4*>(Wb_t + off) = cvt4(v);
        }
        for (int i = lin; i < (DS * DOUT) / 4; i += stride) {   // s: KD=256
            int col = i >> 6, k4 = i & 63;
            float4 v = reinterpret_cast<const float4*>(Ws)[i];
            size_t off = (size_t)(k4 >> 3) * (DOUT * 32) + col * 32 + (k4 & 7) * 4;
            *reinterpret_cast<ushort4*>(Wb_s + off) = cvt4(v);
        }
        return;
    }

    {
#pragma clang fp contract(off)
        int b = bid;
        const float* base = xyz + (size_t)b * NPTS * 3;

        __shared__ float cx[NPTS], cy[NPTS], cz[NPTS];   // 96 KB coord table
        __shared__ u64 rkey[2][8];

        float px[16], py[16], pz[16], dd[16];
#pragma unroll
        for (int i = 0; i < 16; ++i) {
            int p = tid + i * 512;
            px[i] = base[p * 3 + 0];
            py[i] = base[p * 3 + 1];
            pz[i] = base[p * 3 + 2];
            dd[i] = 1e10f;
            cx[p] = px[i]; cy[p] = py[i]; cz[p] = pz[i];
        }

        float lx = base[0], ly = base[1], lz = base[2];
        if (tid == 0) {
            new_xyz[((size_t)b * SPTS + 0) * 3 + 0] = lx;
            new_xyz[((size_t)b * SPTS + 0) * 3 + 1] = ly;
            new_xyz[((size_t)b * SPTS + 0) * 3 + 2] = lz;
        }

        int w = tid >> 6;
        for (int it = 1; it < SPTS; ++it) {
            int par = it & 1;
            u64 bk = 0;
#pragma unroll
            for (int i = 0; i < 16; ++i) {
                float dx = px[i] - lx, dy = py[i] - ly, dz = pz[i] - lz;
                float d = dx * dx + dy * dy;
                d = d + dz * dz;
                float nd = fminf(dd[i], d);
                dd[i] = nd;
                u64 kd = ((u64)__float_as_uint(nd) << 32) | (unsigned)(8191 - (tid + i * 512));
                bk = (kd > bk) ? kd : bk;
            }
#pragma unroll
            for (int off = 1; off < 64; off <<= 1) {
                u64 ok = __shfl_xor(bk, off);
                bk = (ok > bk) ? ok : bk;
            }
            if ((tid & 63) == 0) rkey[par][w] = bk;
            __syncthreads();
            u64 nk = rkey[par][0];
#pragma unroll
            for (int w2 = 1; w2 < 8; ++w2) {
                u64 v2 = rkey[par][w2];
                nk = (v2 > nk) ? v2 : nk;
            }
            int idx = 8191 - (int)(unsigned)(nk & 0xFFFFFFFFull);
            lx = cx[idx]; ly = cy[idx]; lz = cz[idx];
            if (tid == 0) {
                new_xyz[((size_t)b * SPTS + it) * 3 + 0] = lx;
                new_xyz[((size_t)b * SPTS + it) * 3 + 1] = ly;
                new_xyz[((size_t)b * SPTS + it) * 3 + 2] = lz;
            }
        }
    }
}

// ==================== K2: KNN (unchanged, passing) ====================
__global__ __launch_bounds__(512) void knn_kernel(const float* __restrict__ xyz_s,
                                                  const float* __restrict__ xyz_t,
                                                  const float* __restrict__ new_xyz,
                                                  int* __restrict__ idx_s,
                                                  int* __restrict__ idx_t) {
#pragma clang fp contract(off)
    int q = blockIdx.x;
    int tid = threadIdx.x;
    int w = tid >> 6, lane = tid & 63;
    int set = w >> 2;
    int sw = w & 3;
    int b = q >> 5;

    const float* pts = (set ? xyz_t : xyz_s) + (size_t)b * NPTS * 3;

    float qx = new_xyz[q * 3 + 0];
    float qy = new_xyz[q * 3 + 1];
    float qz = new_xyz[q * 3 + 2];
    float qq = qx * qx + qy * qy;
    qq = qq + qz * qz;

    u64 bd[12];
#pragma unroll
    for (int j = 0; j < 12; ++j) bd[j] = ~0ULL;

    for (int i = 0; i < 2048 / 64; ++i) {
        int p = sw * 2048 + i * 64 + lane;
        float p0 = pts[p * 3 + 0], p1 = pts[p * 3 + 1], p2 = pts[p * 3 + 2];
        float pp = p0 * p0 + p1 * p1; pp = pp + p2 * p2;
        float dot = qx * p0 + qy * p1; dot = dot + qz * p2;
        float d = (qq - 2.0f * dot) + pp;
        unsigned u = __float_as_uint(d);
        u = (u & 0x80000000u) ? ~u : (u | 0x80000000u);
        u64 key = ((u64)u << 32) | (unsigned)p;
        if (key < bd[11]) {
#pragma unroll
            for (int j = 11; j > 0; --j) {
                bool keep = (key >= bd[j]);
                u64 sh = (key >= bd[j - 1]) ? key : bd[j - 1];
                bd[j] = keep ? bd[j] : sh;
            }
            if (key < bd[0]) bd[0] = key;
        }
    }

    __shared__ u64 sd[2][48];

#pragma unroll
    for (int r = 0; r < KNN_K; ++r) {
        u64 cv = bd[0];
#pragma unroll
        for (int off = 1; off < 64; off <<= 1) {
            u64 ov = __shfl_xor(cv, off);
            cv = (ov < cv) ? ov : cv;
        }
        if (lane == 0) sd[set][sw * KNN_K + r] = cv;
        if (cv == bd[0]) {
#pragma unroll
            for (int j = 0; j < 11; ++j) bd[j] = bd[j + 1];
            bd[11] = ~0ULL;
        }
    }
    __syncthreads();

    if (sw == 0) {
        int* outp = (set ? idx_t : idx_s) + q * KNN_K;
        u64 cd = (lane < 48) ? sd[set][lane] : ~0ULL;
#pragma unroll
        for (int r = 0; r < KNN_K; ++r) {
            u64 mv = cd;
#pragma unroll
            for (int off = 1; off < 64; off <<= 1) {
                u64 ov = __shfl_xor(mv, off);
                mv = (ov < mv) ? ov : mv;
            }
            if (lane == 0) outp[r] = (int)(unsigned)(mv & 0xFFFFFFFFull);
            if (cd == mv) cd = ~0ULL;
        }
    }
}

// ==================== K3: stage-all-A GEMM ====================
// Block = 4 queries (64 rows, 12 valid/query) x ALL 1024 cols; 8 waves x 128 cols.
// A resident in LDS [64][KD+8] bf16 (row stride pad-8 -> 2-way banks, free).
// Stage: 8 thr/row x float4, NJ=KD/32 independent gathers/thread -> ONE barrier.
// Compute: NK k-steps, no barriers: 4 ds_read_b128 + 8 dense 1KB B-loads + 32 MFMA.
// A frag: lane row=lane&15, k=(lane>>4)*8+e (16x16x32). C/D: col=lane&15,
// row=(lane>>4)*4+reg. Pad rows 12..15 zeroed and masked in epilogue.
template <int KD>
__device__ __forceinline__ void gemm_body(int qg, const float* __restrict__ feat,
                                          const int* __restrict__ idx,
                                          const ushort_t* __restrict__ Wb,
                                          const float* __restrict__ bias,
                                          const float* __restrict__ gamma,
                                          const float* __restrict__ beta,
                                          const float* __restrict__ mean,
                                          const float* __restrict__ var,
                                          float* __restrict__ out,
                                          ushort_t* __restrict__ abuf) {
    const int NK = KD / 32;
    const int NJ = KD / 32;            // float4 loads per staging thread
    const int STRIDE = KD + 8;         // bf16 elems per LDS row (pad 8)
    int tid = threadIdx.x;
    int w = tid >> 6, lane = tid & 63;
    int lrow = lane & 15, kgrp = lane >> 4;
    int q0 = qg * 4;
    int b = q0 >> 5;

    // ---- stage ALL of A: 8 threads/row, NJ float4 gathers each ----
    int r = tid >> 3, seg = tid & 7;
    int sk = r & 15;
    bool valid = (sk < KNN_K);
    int src = valid ? idx[(q0 + (r >> 4)) * KNN_K + sk] : 0;
    const float* srcp = feat + ((size_t)b * NPTS + src) * KD + seg * 4;
    ushort_t* wbase = abuf + (size_t)r * STRIDE + seg * 4;

    const float4 fz = {0.f, 0.f, 0.f, 0.f};
#pragma unroll 4
    for (int j = 0; j < NJ; ++j) {
        float4 v = valid ? *reinterpret_cast<const float4*>(srcp + j * 32) : fz;
        *reinterpret_cast<ushort4*>(wbase + j * 32) = cvt4(v);
    }
    __syncthreads();   // the ONLY barrier

    // ---- barrier-free compute ----
    f32x4 acc[4][8];
#pragma unroll
    for (int mf = 0; mf < 4; ++mf)
#pragma unroll
        for (int nf = 0; nf < 8; ++nf) {
            f32x4 z = {0.f, 0.f, 0.f, 0.f};
            acc[mf][nf] = z;
        }

    int colbase = w * 128;
#pragma unroll 2
    for (int kk = 0; kk < NK; ++kk) {
        bf16x8 a[4];
#pragma unroll
        for (int mf = 0; mf < 4; ++mf)
            a[mf] = *reinterpret_cast<const bf16x8*>(
                abuf + (size_t)(mf * 16 + lrow) * STRIDE + kk * 32 + kgrp * 8);
#pragma unroll
        for (int nf = 0; nf < 8; ++nf) {
            int col = colbase + nf * 16 + lrow;
            const ushort_t* bp = Wb + (size_t)kk * (DOUT * 32) + (size_t)col * 32 + kgrp * 8;
            bf16x8 bfr = *reinterpret_cast<const bf16x8*>(bp);
#pragma unroll
            for (int mf = 0; mf < 4; ++mf)
                acc[mf][nf] = __builtin_amdgcn_mfma_f32_16x16x32_bf16(a[mf], bfr, acc[mf][nf], 0, 0, 0);
        }
    }

    // ---- epilogue: BN + ReLU + max over rows 0..11 ----
#pragma unroll
    for (int nf = 0; nf < 8; ++nf) {
        int col = colbase + nf * 16 + lrow;
        float sc = gamma[col] / sqrtf(var[col] + 1e-5f);
        float sh = (bias[col] - mean[col]) * sc + beta[col];
#pragma unroll
        for (int mf = 0; mf < 4; ++mf) {
            float m;
            if (kgrp < 3) {
                float y0 = fmaxf(acc[mf][nf][0] * sc + sh, 0.0f);
                float y1 = fmaxf(acc[mf][nf][1] * sc + sh, 0.0f);
                float y2 = fmaxf(acc[mf][nf][2] * sc + sh, 0.0f);
                float y3 = fmaxf(acc[mf][nf][3] * sc + sh, 0.0f);
                m = fmaxf(fmaxf(y0, y1), fmaxf(y2, y3));
            } else {
                m = -1e30f;   // pad rows 12..15
            }
            m = fmaxf(m, __shfl_xor(m, 16));
            m = fmaxf(m, __shfl_xor(m, 32));
            if (kgrp == 0) out[(size_t)(q0 + mf) * DOUT + col] = m;
        }
    }
}

struct GP {
    const float* feature_s; const float* feature_t;
    const int* idx_s; const int* idx_t;
    const ushort_t* Wb_s; const ushort_t* Wb_t;
    const float* bias_s; const float* gamma_s; const float* beta_s;
    const float* mean_s; const float* var_s;
    const float* bias_t; const float* gamma_t; const float* beta_t;
    const float* mean_t; const float* var_t;
    float* out;
};

__global__ __launch_bounds__(512, 1) void gemm_kernel(GP P) {
    __shared__ ushort_t abuf[64 * (DT + 8)];   // 132 KB (K1 precedent: 96KB static OK)
    int bid = blockIdx.x;
    if (bid < 128) {                           // heavy t tasks dispatch first
        gemm_body<DT>(bid, P.feature_t, P.idx_t, P.Wb_t, P.bias_t, P.gamma_t,
                      P.beta_t, P.mean_t, P.var_t, P.out + (size_t)512 * 1024, abuf);
    } else {
        gemm_body<DS>(bid - 128, P.feature_s, P.idx_s, P.Wb_s, P.bias_s, P.gamma_s,
                      P.beta_s, P.mean_s, P.var_s, P.out, abuf);
    }
}

extern "C" void kernel_launch(void* const* d_in, const int* in_sizes, int n_in,
                              void* d_out, int out_size, void* d_ws, size_t ws_size,
                              hipStream_t stream) {
    const float* feature_s = (const float*)d_in[0];
    const float* xyz_s     = (const float*)d_in[1];
    const float* feature_t = (const float*)d_in[2];
    const float* xyz_t     = (const float*)d_in[3];
    const float* Ws        = (const float*)d_in[4];
    const float* Wt        = (const float*)d_in[10];
    float* out = (float*)d_out;

    char* ws = (char*)d_ws;
    float* new_xyz  = (float*)(ws + 0);
    int* idx_s      = (int*)(ws + 8192);
    int* idx_t      = (int*)(ws + 32768);
    ushort_t* Wb_s  = (ushort_t*)(ws + 57344);
    ushort_t* Wb_t  = (ushort_t*)(ws + 581632);

    fps_convw_kernel<<<256, 512, 0, stream>>>(xyz_t, new_xyz, Wt, Wb_t, Ws, Wb_s);
    knn_kernel<<<512, 512, 0, stream>>>(xyz_s, xyz_t, new_xyz, idx_s, idx_t);

    GP P;
    P.feature_s = feature_s; P.feature_t = feature_t;
    P.idx_s = idx_s; P.idx_t = idx_t;
    P.Wb_s = Wb_s; P.Wb_t = Wb_t;
    P.bias_s = (const float*)d_in[5];  P.gamma_s = (const float*)d_in[6];
    P.beta_s = (const float*)d_in[7];  P.mean_s  = (const float*)d_in[8];
    P.var_s  = (const float*)d_in[9];
    P.bias_t = (const float*)d_in[11]; P.gamma_t = (const float*)d_in[12];
    P.beta_t = (const float*)d_in[13]; P.mean_t  = (const float*)d_in[14];
    P.var_t  = (const float*)d_in[15];
    P.out = out;

    gemm_kernel<<<256, 512, 0, stream>>>(P);
}

// Round 16
// 128.564 us; speedup vs baseline: 1.0844x; 1.0844x over previous
//
#include <hip/hip_runtime.h>
#include <hip/hip_bf16.h>

// RelationCos pipeline in 3 kernels:
//   K1: FPS (blocks 0-15, packed-u64 argmax + LDS coord table) || W->bf16 packed (16-255)
//   K2: KNN (512 blocks, 8 waves; packed-u64) -> idx in ws
//   K3: gather-fused GEMM, R9 shape (4q x 512 cols, grid 512, 2 blocks/CU) with a
//       counted-vmcnt schedule (T3/T4): raw s_barrier + lgkmcnt(0) only — A-gather
//       loads stay in flight across barriers (depth-4 register ring), B software-
//       pipelined one k-step ahead. No vmcnt(0) in the loop.

#define NPTS 8192
#define SPTS 32
#define KNN_K 12
#define DS 256
#define DT 1024
#define DOUT 1024

typedef float f32x4 __attribute__((ext_vector_type(4)));
typedef __bf16 bf16x8 __attribute__((ext_vector_type(8)));
typedef unsigned short ushort_t;
typedef unsigned long long u64;

__device__ __forceinline__ ushort_t f2bf(float f) {
    unsigned int u = __float_as_uint(f);
    u += 0x7fffu + ((u >> 16) & 1u);   // RNE
    return (ushort_t)(u >> 16);
}

__device__ __forceinline__ ushort4 cvt4(float4 v) {
    ushort4 u;
    u.x = f2bf(v.x); u.y = f2bf(v.y); u.z = f2bf(v.z); u.w = f2bf(v.w);
    return u;
}

// ==================== K1: FPS || W convert (packed) ====================
// Packed layout: element (col,k) -> [k>>5]*(DOUT*32) + col*32 + (k&31)
__global__ __launch_bounds__(512) void fps_convw_kernel(const float* __restrict__ xyz,
                                                        float* __restrict__ new_xyz,
                                                        const float* __restrict__ Wt,
                                                        ushort_t* __restrict__ Wb_t,
                                                        const float* __restrict__ Ws,
                                                        ushort_t* __restrict__ Wb_s) {
    int bid = blockIdx.x;
    int tid = threadIdx.x;

    if (bid >= 16) {
        int lin = (bid - 16) * 512 + tid;
        const int stride = 240 * 512;
        for (int i = lin; i < (DT * DOUT) / 4; i += stride) {   // t: KD=1024
            int col = i >> 8, k4 = i & 255;
            float4 v = reinterpret_cast<const float4*>(Wt)[i];
            size_t off = (size_t)(k4 >> 3) * (DOUT * 32) + col * 32 + (k4 & 7) * 4;
            *reinterpret_cast<ushort4*>(Wb_t + off) = cvt4(v);
        }
        for (int i = lin; i < (DS * DOUT) / 4; i += stride) {   // s: KD=256
            int col = i >> 6, k4 = i & 63;
            float4 v = reinterpret_cast<const float4*>(Ws)[i];
            size_t off = (size_t)(k4 >> 3) * (DOUT * 32) + col * 32 + (k4 & 7) * 4;
            *reinterpret_cast<ushort4*>(Wb_s + off) = cvt4(v);
        }
        return;
    }

    {
#pragma clang fp contract(off)
        int b = bid;
        const float* base = xyz + (size_t)b * NPTS * 3;

        __shared__ float cx[NPTS], cy[NPTS], cz[NPTS];   // 96 KB coord table
        __shared__ u64 rkey[2][8];

        float px[16], py[16], pz[16], dd[16];
#pragma unroll
        for (int i = 0; i < 16; ++i) {
            int p = tid + i * 512;
            px[i] = base[p * 3 + 0];
            py[i] = base[p * 3 + 1];
            pz[i] = base[p * 3 + 2];
            dd[i] = 1e10f;
            cx[p] = px[i]; cy[p] = py[i]; cz[p] = pz[i];
        }

        float lx = base[0], ly = base[1], lz = base[2];
        if (tid == 0) {
            new_xyz[((size_t)b * SPTS + 0) * 3 + 0] = lx;
            new_xyz[((size_t)b * SPTS + 0) * 3 + 1] = ly;
            new_xyz[((size_t)b * SPTS + 0) * 3 + 2] = lz;
        }

        int w = tid >> 6;
        for (int it = 1; it < SPTS; ++it) {
            int par = it & 1;
            u64 bk = 0;
#pragma unroll
            for (int i = 0; i < 16; ++i) {
                float dx = px[i] - lx, dy = py[i] - ly, dz = pz[i] - lz;
                float d = dx * dx + dy * dy;
                d = d + dz * dz;
                float nd = fminf(dd[i], d);
                dd[i] = nd;
                u64 kd = ((u64)__float_as_uint(nd) << 32) | (unsigned)(8191 - (tid + i * 512));
                bk = (kd > bk) ? kd : bk;
            }
#pragma unroll
            for (int off = 1; off < 64; off <<= 1) {
                u64 ok = __shfl_xor(bk, off);
                bk = (ok > bk) ? ok : bk;
            }
            if ((tid & 63) == 0) rkey[par][w] = bk;
            __syncthreads();
            u64 nk = rkey[par][0];
#pragma unroll
            for (int w2 = 1; w2 < 8; ++w2) {
                u64 v2 = rkey[par][w2];
                nk = (v2 > nk) ? v2 : nk;
            }
            int idx = 8191 - (int)(unsigned)(nk & 0xFFFFFFFFull);
            lx = cx[idx]; ly = cy[idx]; lz = cz[idx];
            if (tid == 0) {
                new_xyz[((size_t)b * SPTS + it) * 3 + 0] = lx;
                new_xyz[((size_t)b * SPTS + it) * 3 + 1] = ly;
                new_xyz[((size_t)b * SPTS + it) * 3 + 2] = lz;
            }
        }
    }
}

// ==================== K2: KNN (unchanged, passing) ====================
__global__ __launch_bounds__(512) void knn_kernel(const float* __restrict__ xyz_s,
                                                  const float* __restrict__ xyz_t,
                                                  const float* __restrict__ new_xyz,
                                                  int* __restrict__ idx_s,
                                                  int* __restrict__ idx_t) {
#pragma clang fp contract(off)
    int q = blockIdx.x;
    int tid = threadIdx.x;
    int w = tid >> 6, lane = tid & 63;
    int set = w >> 2;
    int sw = w & 3;
    int b = q >> 5;

    const float* pts = (set ? xyz_t : xyz_s) + (size_t)b * NPTS * 3;

    float qx = new_xyz[q * 3 + 0];
    float qy = new_xyz[q * 3 + 1];
    float qz = new_xyz[q * 3 + 2];
    float qq = qx * qx + qy * qy;
    qq = qq + qz * qz;

    u64 bd[12];
#pragma unroll
    for (int j = 0; j < 12; ++j) bd[j] = ~0ULL;

    for (int i = 0; i < 2048 / 64; ++i) {
        int p = sw * 2048 + i * 64 + lane;
        float p0 = pts[p * 3 + 0], p1 = pts[p * 3 + 1], p2 = pts[p * 3 + 2];
        float pp = p0 * p0 + p1 * p1; pp = pp + p2 * p2;
        float dot = qx * p0 + qy * p1; dot = dot + qz * p2;
        float d = (qq - 2.0f * dot) + pp;
        unsigned u = __float_as_uint(d);
        u = (u & 0x80000000u) ? ~u : (u | 0x80000000u);
        u64 key = ((u64)u << 32) | (unsigned)p;
        if (key < bd[11]) {
#pragma unroll
            for (int j = 11; j > 0; --j) {
                bool keep = (key >= bd[j]);
                u64 sh = (key >= bd[j - 1]) ? key : bd[j - 1];
                bd[j] = keep ? bd[j] : sh;
            }
            if (key < bd[0]) bd[0] = key;
        }
    }

    __shared__ u64 sd[2][48];

#pragma unroll
    for (int r = 0; r < KNN_K; ++r) {
        u64 cv = bd[0];
#pragma unroll
        for (int off = 1; off < 64; off <<= 1) {
            u64 ov = __shfl_xor(cv, off);
            cv = (ov < cv) ? ov : cv;
        }
        if (lane == 0) sd[set][sw * KNN_K + r] = cv;
        if (cv == bd[0]) {
#pragma unroll
            for (int j = 0; j < 11; ++j) bd[j] = bd[j + 1];
            bd[11] = ~0ULL;
        }
    }
    __syncthreads();

    if (sw == 0) {
        int* outp = (set ? idx_t : idx_s) + q * KNN_K;
        u64 cd = (lane < 48) ? sd[set][lane] : ~0ULL;
#pragma unroll
        for (int r = 0; r < KNN_K; ++r) {
            u64 mv = cd;
#pragma unroll
            for (int off = 1; off < 64; off <<= 1) {
                u64 ov = __shfl_xor(mv, off);
                mv = (ov < mv) ? ov : mv;
            }
            if (lane == 0) outp[r] = (int)(unsigned)(mv & 0xFFFFFFFFull);
            if (cd == mv) cd = ~0ULL;
        }
    }
}

// ==================== K3: counted-vmcnt gather-fused GEMM ====================
// Block = 4 queries (64 rows, 12 valid/query) x 512 cols; 8 waves x 64 cols; grid 512.
// LDS dbuf [2][64][44] bf16 (2-way banks, free). Per k-step: ds_read a-frags from
// buf kk&1; issue A-gather for slab kk+4 into reg ring (depth-4); cvt+ds_write slab
// kk+1 into buf (kk+1)&1 (counted vmcnt via register dep); B for kk+1 loaded before
// the barrier; lgkmcnt(0) + RAW s_barrier (global loads never drained).
template <int KD>
__device__ __forceinline__ void gemm_body(int qg, int ch, const float* __restrict__ feat,
                                          const int* __restrict__ idx,
                                          const ushort_t* __restrict__ Wb,
                                          const float* __restrict__ bias,
                                          const float* __restrict__ gamma,
                                          const float* __restrict__ beta,
                                          const float* __restrict__ mean,
                                          const float* __restrict__ var,
                                          float* __restrict__ out,
                                          ushort_t (*abuf)[64][44]) {
    const int NK = KD / 32;
    static_assert(DT % 128 == 0 && DS % 128 == 0, "NK multiple of 4");
    int tid = threadIdx.x;
    int w = tid >> 6, lane = tid & 63;
    int lrow = lane & 15, kgrp = lane >> 4;
    int q0 = qg * 4;
    int b = q0 >> 5;

    // staging role: 8 threads/row, one float4 each
    int r = tid >> 3, seg = tid & 7;
    int sk = r & 15;
    bool valid = (sk < KNN_K);
    int src = valid ? idx[(q0 + (r >> 4)) * KNN_K + sk] : 0;
    const float* srcp = feat + ((size_t)b * NPTS + src) * KD + seg * 4;

    int colbase = ch * 512 + w * 64;

    f32x4 acc[4][4];
#pragma unroll
    for (int mf = 0; mf < 4; ++mf)
#pragma unroll
        for (int nf = 0; nf < 4; ++nf) {
            f32x4 z = {0.f, 0.f, 0.f, 0.f};
            acc[mf][nf] = z;
        }

    const float4 fz = {0.f, 0.f, 0.f, 0.f};
    float4 g[4];   // A-gather register ring; slab m lives in slot (m-1)&3

    // prologue: slab 0 -> LDS buf 0 directly; slabs 1..3 -> ring slots 0..2
    {
        float4 v = valid ? *reinterpret_cast<const float4*>(srcp) : fz;
        *reinterpret_cast<ushort4*>(&abuf[0][r][seg * 4]) = cvt4(v);
    }
#pragma unroll
    for (int m = 1; m < 4; ++m)
        g[m - 1] = (m < NK && valid) ? *reinterpret_cast<const float4*>(srcp + m * 32) : fz;
    g[3] = fz;
    // B for k-step 0
    bf16x8 b0[4], b1[4];
#pragma unroll
    for (int nf = 0; nf < 4; ++nf)
        b0[nf] = *reinterpret_cast<const bf16x8*>(
            Wb + (size_t)(colbase + nf * 16 + lrow) * 32 + kgrp * 8);
    asm volatile("s_waitcnt lgkmcnt(0)" ::: "memory");
    __builtin_amdgcn_s_barrier();

#pragma unroll
    for (int kk = 0; kk < NK; ++kk) {
        // a-frags from current buffer (written before last barrier)
        bf16x8 a[4];
#pragma unroll
        for (int mf = 0; mf < 4; ++mf)
            a[mf] = *reinterpret_cast<const bf16x8*>(&abuf[kk & 1][mf * 16 + lrow][kgrp * 8]);

        // issue A-gather for slab kk+4 into ring slot (kk+3)&3
        if (kk + 4 < NK)
            g[(kk + 3) & 3] = valid ? *reinterpret_cast<const float4*>(srcp + (kk + 4) * 32) : fz;

        // cvt+write slab kk+1 (loaded 3 steps ago -> counted vmcnt) into other buffer
        if (kk + 1 < NK)
            *reinterpret_cast<ushort4*>(&abuf[(kk + 1) & 1][r][seg * 4]) = cvt4(g[kk & 3]);

        // B for k-step kk+1 (overlaps MFMA + barrier)
        if (kk + 1 < NK) {
#pragma unroll
            for (int nf = 0; nf < 4; ++nf) {
                const ushort_t* bp = Wb + (size_t)(kk + 1) * (DOUT * 32)
                                     + (size_t)(colbase + nf * 16 + lrow) * 32 + kgrp * 8;
                if ((kk & 1) == 0) b1[nf] = *reinterpret_cast<const bf16x8*>(bp);
                else               b0[nf] = *reinterpret_cast<const bf16x8*>(bp);
            }
        }

        // MFMA with this step's B
#pragma unroll
        for (int nf = 0; nf < 4; ++nf) {
            bf16x8 bfr = ((kk & 1) == 0) ? b0[nf] : b1[nf];
#pragma unroll
            for (int mf = 0; mf < 4; ++mf)
                acc[mf][nf] = __builtin_amdgcn_mfma_f32_16x16x32_bf16(a[mf], bfr, acc[mf][nf], 0, 0, 0);
        }

        // writer-side LDS drain only; global loads stay in flight
        asm volatile("s_waitcnt lgkmcnt(0)" ::: "memory");
        __builtin_amdgcn_s_barrier();
    }

    // epilogue: BN + ReLU + max over rows 0..11 (frag rows = kgrp*4+e; kgrp==3 pads)
#pragma unroll
    for (int nf = 0; nf < 4; ++nf) {
        int col = colbase + nf * 16 + lrow;
        float sc = gamma[col] / sqrtf(var[col] + 1e-5f);
        float sh = (bias[col] - mean[col]) * sc + beta[col];
#pragma unroll
        for (int mf = 0; mf < 4; ++mf) {
            float m;
            if (kgrp < 3) {
                float y0 = fmaxf(acc[mf][nf][0] * sc + sh, 0.0f);
                float y1 = fmaxf(acc[mf][nf][1] * sc + sh, 0.0f);
                float y2 = fmaxf(acc[mf][nf][2] * sc + sh, 0.0f);
                float y3 = fmaxf(acc[mf][nf][3] * sc + sh, 0.0f);
                m = fmaxf(fmaxf(y0, y1), fmaxf(y2, y3));
            } else {
                m = -1e30f;
            }
            m = fmaxf(m, __shfl_xor(m, 16));
            m = fmaxf(m, __shfl_xor(m, 32));
            if (kgrp == 0) out[(size_t)(q0 + mf) * DOUT + col] = m;
        }
    }
}

struct GP {
    const float* feature_s; const float* feature_t;
    const int* idx_s; const int* idx_t;
    const ushort_t* Wb_s; const ushort_t* Wb_t;
    const float* bias_s; const float* gamma_s; const float* beta_s;
    const float* mean_s; const float* var_s;
    const float* bias_t; const float* gamma_t; const float* beta_t;
    const float* mean_t; const float* var_t;
    float* out;
};

__global__ __launch_bounds__(512, 2) void gemm_kernel(GP P) {
    __shared__ ushort_t abuf[2][64][44];   // 11.3 KB
    int bid = blockIdx.x;
    bool is_t = (bid < 256);               // heavy t tasks dispatch first
    int r2 = is_t ? bid : bid - 256;
    int qg = r2 >> 1, ch = r2 & 1;         // 128 query-groups x 2 col-halves
    if (is_t) {
        gemm_body<DT>(qg, ch, P.feature_t, P.idx_t, P.Wb_t, P.bias_t, P.gamma_t,
                      P.beta_t, P.mean_t, P.var_t, P.out + (size_t)512 * 1024, abuf);
    } else {
        gemm_body<DS>(qg, ch, P.feature_s, P.idx_s, P.Wb_s, P.bias_s, P.gamma_s,
                      P.beta_s, P.mean_s, P.var_s, P.out, abuf);
    }
}

extern "C" void kernel_launch(void* const* d_in, const int* in_sizes, int n_in,
                              void* d_out, int out_size, void* d_ws, size_t ws_size,
                              hipStream_t stream) {
    const float* feature_s = (const float*)d_in[0];
    const float* xyz_s     = (const float*)d_in[1];
    const float* feature_t = (const float*)d_in[2];
    const float* xyz_t     = (const float*)d_in[3];
    const float* Ws        = (const float*)d_in[4];
    const float* Wt        = (const float*)d_in[10];
    float* out = (float*)d_out;

    char* ws = (char*)d_ws;
    float* new_xyz  = (float*)(ws + 0);
    int* idx_s      = (int*)(ws + 8192);
    int* idx_t      = (int*)(ws + 32768);
    ushort_t* Wb_s  = (ushort_t*)(ws + 57344);
    ushort_t* Wb_t  = (ushort_t*)(ws + 581632);

    fps_convw_kernel<<<256, 512, 0, stream>>>(xyz_t, new_xyz, Wt, Wb_t, Ws, Wb_s);
    knn_kernel<<<512, 512, 0, stream>>>(xyz_s, xyz_t, new_xyz, idx_s, idx_t);

    GP P;
    P.feature_s = feature_s; P.feature_t = feature_t;
    P.idx_s = idx_s; P.idx_t = idx_t;
    P.Wb_s = Wb_s; P.Wb_t = Wb_t;
    P.bias_s = (const float*)d_in[5];  P.gamma_s = (const float*)d_in[6];
    P.beta_s = (const float*)d_in[7];  P.mean_s  = (const float*)d_in[8];
    P.var_s  = (const float*)d_in[9];
    P.bias_t = (const float*)d_in[11]; P.gamma_t = (const float*)d_in[12];
    P.beta_t = (const float*)d_in[13]; P.mean_t  = (const float*)d_in[14];
    P.var_t  = (const float*)d_in[15];
    P.out = out;

    gemm_kernel<<<512, 512, 0, stream>>>(P);
}

// Round 17
// 127.232 us; speedup vs baseline: 1.0958x; 1.0105x over previous
//
#include <hip/hip_runtime.h>
#include <hip/hip_bf16.h>

// RelationCos pipeline in 3 kernels (R9 known-best + FPS reduce-chain cut):
//   K1: FPS (blocks 0-15; f32 shuffle-max + ballot tie-resolve) || W->bf16 packed (16-255)
//   K2: KNN (512 blocks, 8 waves; packed-u64)  [R9 exact]
//   K3: gather-fused GEMM (4q x 512 cols, grid 512) [R9 exact; LDS pad 40->44]

#define NPTS 8192
#define SPTS 32
#define KNN_K 12
#define DS 256
#define DT 1024
#define DOUT 1024

typedef float f32x4 __attribute__((ext_vector_type(4)));
typedef __bf16 bf16x8 __attribute__((ext_vector_type(8)));
typedef unsigned short ushort_t;
typedef unsigned long long u64;

__device__ __forceinline__ ushort_t f2bf(float f) {
    unsigned int u = __float_as_uint(f);
    u += 0x7fffu + ((u >> 16) & 1u);   // RNE
    return (ushort_t)(u >> 16);
}

__device__ __forceinline__ ushort4 cvt4(float4 v) {
    ushort4 u;
    u.x = f2bf(v.x); u.y = f2bf(v.y); u.z = f2bf(v.z); u.w = f2bf(v.w);
    return u;
}

// ==================== K1: FPS || W convert (packed) ====================
// Packed layout: element (col,k) -> [k>>5]*(DOUT*32) + col*32 + (k&31)
__global__ __launch_bounds__(512) void fps_convw_kernel(const float* __restrict__ xyz,
                                                        float* __restrict__ new_xyz,
                                                        const float* __restrict__ Wt,
                                                        ushort_t* __restrict__ Wb_t,
                                                        const float* __restrict__ Ws,
                                                        ushort_t* __restrict__ Wb_s) {
    int bid = blockIdx.x;
    int tid = threadIdx.x;

    if (bid >= 16) {
        int lin = (bid - 16) * 512 + tid;
        const int stride = 240 * 512;
        for (int i = lin; i < (DT * DOUT) / 4; i += stride) {   // t: KD=1024
            int col = i >> 8, k4 = i & 255;
            float4 v = reinterpret_cast<const float4*>(Wt)[i];
            size_t off = (size_t)(k4 >> 3) * (DOUT * 32) + col * 32 + (k4 & 7) * 4;
            *reinterpret_cast<ushort4*>(Wb_t + off) = cvt4(v);
        }
        for (int i = lin; i < (DS * DOUT) / 4; i += stride) {   // s: KD=256
            int col = i >> 6, k4 = i & 63;
            float4 v = reinterpret_cast<const float4*>(Ws)[i];
            size_t off = (size_t)(k4 >> 3) * (DOUT * 32) + col * 32 + (k4 & 7) * 4;
            *reinterpret_cast<ushort4*>(Wb_s + off) = cvt4(v);
        }
        return;
    }

    // ---- FPS: one block per batch; f32 shuffle-max + ballot tie-resolution ----
    {
#pragma clang fp contract(off)
        int b = bid;
        const float* base = xyz + (size_t)b * NPTS * 3;

        __shared__ float cx[NPTS], cy[NPTS], cz[NPTS];   // 96 KB coord table
        __shared__ float rv[2][8];
        __shared__ int ri[2][8];

        float px[16], py[16], pz[16], dd[16];
#pragma unroll
        for (int i = 0; i < 16; ++i) {
            int p = tid + i * 512;
            px[i] = base[p * 3 + 0];
            py[i] = base[p * 3 + 1];
            pz[i] = base[p * 3 + 2];
            dd[i] = 1e10f;
            cx[p] = px[i]; cy[p] = py[i]; cz[p] = pz[i];
        }

        float lx = base[0], ly = base[1], lz = base[2];
        if (tid == 0) {
            new_xyz[((size_t)b * SPTS + 0) * 3 + 0] = lx;
            new_xyz[((size_t)b * SPTS + 0) * 3 + 1] = ly;
            new_xyz[((size_t)b * SPTS + 0) * 3 + 2] = lz;
        }

        int w = tid >> 6;
        for (int it = 1; it < SPTS; ++it) {
            int par = it & 1;
            float bv = -1.0f;
            int bi = NPTS;
#pragma unroll
            for (int i = 0; i < 16; ++i) {
                float dx = px[i] - lx, dy = py[i] - ly, dz = pz[i] - lz;
                float d = dx * dx + dy * dy;
                d = d + dz * dz;
                float nd = fminf(dd[i], d);
                dd[i] = nd;
                bool t = nd > bv;   // strict >: keeps FIRST in-lane idx (ascending)
                bv = t ? nd : bv;
                bi = t ? (tid + i * 512) : bi;
            }
            // wave max on f32 only (single-instr shuffles)
            float mv = bv;
#pragma unroll
            for (int off = 1; off < 64; off <<= 1)
                mv = fmaxf(mv, __shfl_xor(mv, off));
            // exact tie-resolution: min idx among lanes holding mv
            u64 mask = __ballot(bv == mv);
            int ii;
            int l0 = (int)__builtin_ctzll(mask);
            ii = __shfl(bi, l0);
            u64 rest = mask & (mask - 1);
            if (rest) {                      // rare multi-lane tie (wave-uniform branch)
                while (rest) {
                    int l = (int)__builtin_ctzll(rest);
                    int c = __shfl(bi, l);
                    ii = (c < ii) ? c : ii;
                    rest &= rest - 1;
                }
            }
            if ((tid & 63) == 0) { rv[par][w] = mv; ri[par][w] = ii; }
            __syncthreads();   // one barrier/iter (parity dbuf); also covers cx fill
            float nv = rv[par][0];
            int nidx = ri[par][0];
#pragma unroll
            for (int w2 = 1; w2 < 8; ++w2) {
                float v2 = rv[par][w2];
                int i2 = ri[par][w2];
                bool t = (v2 > nv) || (v2 == nv && i2 < nidx);
                nv = t ? v2 : nv;
                nidx = t ? i2 : nidx;
            }
            lx = cx[nidx]; ly = cy[nidx]; lz = cz[nidx];   // LDS broadcast
            if (tid == 0) {
                new_xyz[((size_t)b * SPTS + it) * 3 + 0] = lx;
                new_xyz[((size_t)b * SPTS + it) * 3 + 1] = ly;
                new_xyz[((size_t)b * SPTS + it) * 3 + 2] = lz;
            }
        }
    }
}

// ==================== K2: KNN (R9 exact) ====================
__global__ __launch_bounds__(512) void knn_kernel(const float* __restrict__ xyz_s,
                                                  const float* __restrict__ xyz_t,
                                                  const float* __restrict__ new_xyz,
                                                  int* __restrict__ idx_s,
                                                  int* __restrict__ idx_t) {
#pragma clang fp contract(off)
    int q = blockIdx.x;
    int tid = threadIdx.x;
    int w = tid >> 6, lane = tid & 63;
    int set = w >> 2;
    int sw = w & 3;
    int b = q >> 5;

    const float* pts = (set ? xyz_t : xyz_s) + (size_t)b * NPTS * 3;

    float qx = new_xyz[q * 3 + 0];
    float qy = new_xyz[q * 3 + 1];
    float qz = new_xyz[q * 3 + 2];
    float qq = qx * qx + qy * qy;
    qq = qq + qz * qz;

    u64 bd[12];
#pragma unroll
    for (int j = 0; j < 12; ++j) bd[j] = ~0ULL;

    for (int i = 0; i < 2048 / 64; ++i) {
        int p = sw * 2048 + i * 64 + lane;
        float p0 = pts[p * 3 + 0], p1 = pts[p * 3 + 1], p2 = pts[p * 3 + 2];
        float pp = p0 * p0 + p1 * p1; pp = pp + p2 * p2;
        float dot = qx * p0 + qy * p1; dot = dot + qz * p2;
        float d = (qq - 2.0f * dot) + pp;
        unsigned u = __float_as_uint(d);
        u = (u & 0x80000000u) ? ~u : (u | 0x80000000u);
        u64 key = ((u64)u << 32) | (unsigned)p;
        if (key < bd[11]) {
#pragma unroll
            for (int j = 11; j > 0; --j) {
                bool keep = (key >= bd[j]);
                u64 sh = (key >= bd[j - 1]) ? key : bd[j - 1];
                bd[j] = keep ? bd[j] : sh;
            }
            if (key < bd[0]) bd[0] = key;
        }
    }

    __shared__ u64 sd[2][48];

#pragma unroll
    for (int r = 0; r < KNN_K; ++r) {
        u64 cv = bd[0];
#pragma unroll
        for (int off = 1; off < 64; off <<= 1) {
            u64 ov = __shfl_xor(cv, off);
            cv = (ov < cv) ? ov : cv;
        }
        if (lane == 0) sd[set][sw * KNN_K + r] = cv;
        if (cv == bd[0]) {
#pragma unroll
            for (int j = 0; j < 11; ++j) bd[j] = bd[j + 1];
            bd[11] = ~0ULL;
        }
    }
    __syncthreads();

    if (sw == 0) {
        int* outp = (set ? idx_t : idx_s) + q * KNN_K;
        u64 cd = (lane < 48) ? sd[set][lane] : ~0ULL;
#pragma unroll
        for (int r = 0; r < KNN_K; ++r) {
            u64 mv = cd;
#pragma unroll
            for (int off = 1; off < 64; off <<= 1) {
                u64 ov = __shfl_xor(mv, off);
                mv = (ov < mv) ? ov : mv;
            }
            if (lane == 0) outp[r] = (int)(unsigned)(mv & 0xFFFFFFFFull);
            if (cd == mv) cd = ~0ULL;
        }
    }
}

// ==================== K3: gather-fused GEMM (R9 exact; pad 40->44) ====================
// Block = 4 queries (64 rows, 12 valid/query) x 512 cols; 8 waves x 64 cols; grid 512.
// LDS dbuf [2][64][44] (stride 22 dwords -> 2-way banks, free). Depth-1 prefetch,
// one __syncthreads per k-step. B dense 1KB wave-loads from packed Wb.
template <int KD>
__device__ __forceinline__ void gemm_body(int mblk, int ch, const float* __restrict__ feat,
                                          const int* __restrict__ idx,
                                          const ushort_t* __restrict__ Wb,
                                          const float* __restrict__ bias,
                                          const float* __restrict__ gamma,
                                          const float* __restrict__ beta,
                                          const float* __restrict__ mean,
                                          const float* __restrict__ var,
                                          float* __restrict__ out,
                                          ushort_t (*abuf)[64][44]) {
    const int NK = KD / 32;
    int tid = threadIdx.x;
    int w = tid >> 6, lane = tid & 63;
    int lrow = lane & 15, kgrp = lane >> 4;

    // staging role: 8 threads per row, 4 floats each
    int r = tid >> 3, seg = tid & 7;
    int q = mblk * 4 + (r >> 4);
    int k = r & 15;
    bool valid = (k < KNN_K);
    int b = q >> 5;
    int src = valid ? idx[q * KNN_K + k] : 0;
    const float* srcp = feat + ((size_t)b * NPTS + src) * KD + seg * 4;

    f32x4 acc[4][4];
#pragma unroll
    for (int mi = 0; mi < 4; ++mi)
#pragma unroll
        for (int ni = 0; ni < 4; ++ni) {
            f32x4 z = {0.f, 0.f, 0.f, 0.f};
            acc[mi][ni] = z;
        }

    // prologue: stage slab 0
    {
        float4 v = {0.f, 0.f, 0.f, 0.f};
        if (valid) v = *reinterpret_cast<const float4*>(srcp);
        *reinterpret_cast<ushort4*>(&abuf[0][r][seg * 4]) = cvt4(v);
    }
    __syncthreads();

    for (int kk = 0; kk < NK; ++kk) {
        int cur = kk & 1;
        float4 nv = {0.f, 0.f, 0.f, 0.f};
        if (kk + 1 < NK && valid)
            nv = *reinterpret_cast<const float4*>(srcp + (kk + 1) * 32);

        bf16x8 a[4];
#pragma unroll
        for (int mf = 0; mf < 4; ++mf)
            a[mf] = *reinterpret_cast<const bf16x8*>(&abuf[cur][mf * 16 + lrow][kgrp * 8]);

#pragma unroll
        for (int nf = 0; nf < 4; ++nf) {
            int col = ch * 512 + w * 64 + nf * 16 + lrow;
            const ushort_t* bp = Wb + (size_t)kk * (DOUT * 32) + (size_t)col * 32 + kgrp * 8;
            bf16x8 bfr = *reinterpret_cast<const bf16x8*>(bp);
#pragma unroll
            for (int mf = 0; mf < 4; ++mf)
                acc[mf][nf] = __builtin_amdgcn_mfma_f32_16x16x32_bf16(a[mf], bfr, acc[mf][nf], 0, 0, 0);
        }

        if (kk + 1 < NK)
            *reinterpret_cast<ushort4*>(&abuf[cur ^ 1][r][seg * 4]) = cvt4(nv);
        __syncthreads();
    }

    // epilogue: BN + ReLU + max over rows 0..11 (frag rows = kgrp*4+e; kgrp==3 pads)
#pragma unroll
    for (int nf = 0; nf < 4; ++nf) {
        int col = ch * 512 + w * 64 + nf * 16 + lrow;
        float sc = gamma[col] / sqrtf(var[col] + 1e-5f);
        float sh = (bias[col] - mean[col]) * sc + beta[col];
#pragma unroll
        for (int mf = 0; mf < 4; ++mf) {
            float m;
            if (kgrp < 3) {
                float y0 = fmaxf(acc[mf][nf][0] * sc + sh, 0.0f);
                float y1 = fmaxf(acc[mf][nf][1] * sc + sh, 0.0f);
                float y2 = fmaxf(acc[mf][nf][2] * sc + sh, 0.0f);
                float y3 = fmaxf(acc[mf][nf][3] * sc + sh, 0.0f);
                m = fmaxf(fmaxf(y0, y1), fmaxf(y2, y3));
            } else {
                m = -1e30f;
            }
            m = fmaxf(m, __shfl_xor(m, 16));
            m = fmaxf(m, __shfl_xor(m, 32));
            if (kgrp == 0) out[(size_t)(mblk * 4 + mf) * DOUT + col] = m;
        }
    }
}

struct GP {
    const float* feature_s; const float* feature_t;
    const int* idx_s; const int* idx_t;
    const ushort_t* Wb_s; const ushort_t* Wb_t;
    const float* bias_s; const float* gamma_s; const float* beta_s;
    const float* mean_s; const float* var_s;
    const float* bias_t; const float* gamma_t; const float* beta_t;
    const float* mean_t; const float* var_t;
    float* out;
};

__global__ __launch_bounds__(512, 4) void gemm_kernel(GP P) {
    __shared__ ushort_t abuf[2][64][44];   // 11.3 KB
    int bid = blockIdx.x;
    bool is_t = (bid < 256);               // heavy t tasks dispatch first
    int r2 = bid & 255;
    int mblk = r2 >> 1, ch = r2 & 1;
    if (is_t) {
        gemm_body<DT>(mblk, ch, P.feature_t, P.idx_t, P.Wb_t, P.bias_t, P.gamma_t,
                      P.beta_t, P.mean_t, P.var_t, P.out + (size_t)512 * 1024, abuf);
    } else {
        gemm_body<DS>(mblk, ch, P.feature_s, P.idx_s, P.Wb_s, P.bias_s, P.gamma_s,
                      P.beta_s, P.mean_s, P.var_s, P.out, abuf);
    }
}

extern "C" void kernel_launch(void* const* d_in, const int* in_sizes, int n_in,
                              void* d_out, int out_size, void* d_ws, size_t ws_size,
                              hipStream_t stream) {
    const float* feature_s = (const float*)d_in[0];
    const float* xyz_s     = (const float*)d_in[1];
    const float* feature_t = (const float*)d_in[2];
    const float* xyz_t     = (const float*)d_in[3];
    const float* Ws        = (const float*)d_in[4];
    const float* Wt        = (const float*)d_in[10];
    float* out = (float*)d_out;

    char* ws = (char*)d_ws;
    float* new_xyz  = (float*)(ws + 0);
    int* idx_s      = (int*)(ws + 8192);
    int* idx_t      = (int*)(ws + 32768);
    ushort_t* Wb_s  = (ushort_t*)(ws + 57344);
    ushort_t* Wb_t  = (ushort_t*)(ws + 581632);

    fps_convw_kernel<<<256, 512, 0, stream>>>(xyz_t, new_xyz, Wt, Wb_t, Ws, Wb_s);
    knn_kernel<<<512, 512, 0, stream>>>(xyz_s, xyz_t, new_xyz, idx_s, idx_t);

    GP P;
    P.feature_s = feature_s; P.feature_t = feature_t;
    P.idx_s = idx_s; P.idx_t = idx_t;
    P.Wb_s = Wb_s; P.Wb_t = Wb_t;
    P.bias_s = (const float*)d_in[5];  P.gamma_s = (const float*)d_in[6];
    P.beta_s = (const float*)d_in[7];  P.mean_s  = (const float*)d_in[8];
    P.var_s  = (const float*)d_in[9];
    P.bias_t = (const float*)d_in[11]; P.gamma_t = (const float*)d_in[12];
    P.beta_t = (const float*)d_in[13]; P.mean_t  = (const float*)d_in[14];
    P.var_t  = (const float*)d_in[15];
    P.out = out;

    gemm_kernel<<<512, 512, 0, stream>>>(P);
}